// Round 10
// baseline (188.521 us; speedup 1.0000x reference)
//
#include <hip/hip_runtime.h>
#include <math.h>

#define NEXP 64
#define TOPK 8

typedef float v4 __attribute__((ext_vector_type(4)));

// ---------------- K1: top-k + softmax denom + tw/ti/hist + sinv ----------------
// Thread-per-token. Lane reads its own 256B row (divergent-contiguous: each
// 64B line fully consumed by one lane -> no over-fetch; R4 evidence).
// Single consume-and-discard pass keeps VGPR low -> high TLP.
__global__ __launch_bounds__(256) void topk_kernel(
    const float* __restrict__ logits,
    float* __restrict__ out_tw,
    float* __restrict__ out_ti,
    float* __restrict__ out_hist,
    float* __restrict__ sinv_ws)
{
    __shared__ float shist[NEXP];
    const int tid = threadIdx.x;
    if (tid < NEXP) shist[tid] = 0.0f;
    __syncthreads();

    const long tok = (long)blockIdx.x * 256 + tid;
    const v4* g = (const v4*)logits + tok * (NEXP / 4);

    float vals[TOPK], ids[TOPK];
    #pragma unroll
    for (int j = 0; j < TOPK; ++j) { vals[j] = -INFINITY; ids[j] = 0.0f; }
    float ssum = 0.0f;

    #pragma unroll
    for (int k = 0; k < 16; ++k) {
        v4 x4 = __builtin_nontemporal_load(&g[k]);
        #pragma unroll
        for (int u = 0; u < 4; ++u) {
            float x = x4[u];
            ssum += __expf(x);
            float fe = (float)(k * 4 + u);
            bool c[TOPK];
            #pragma unroll
            for (int j = 0; j < TOPK; ++j) c[j] = x > vals[j];
            #pragma unroll
            for (int j = TOPK - 1; j >= 1; --j) {
                ids[j]  = c[j] ? (c[j - 1] ? ids[j - 1] : fe) : ids[j];
                vals[j] = __builtin_amdgcn_fmed3f(x, vals[j - 1], vals[j]);
            }
            ids[0]  = c[0] ? fe : ids[0];
            vals[0] = fmaxf(vals[0], x);
        }
    }
    sinv_ws[tok] = 1.0f / ssum;               // coalesced 4B/lane

    // top-k weights from registers (softmax denominator cancels)
    float ew[TOPK];
    float tsum = 0.0f;
    #pragma unroll
    for (int j = 0; j < TOPK; ++j) { ew[j] = __expf(vals[j]); tsum += ew[j]; }
    const float tinv = 1.0f / tsum;

    v4* twp = (v4*)out_tw + tok * 2;
    v4* tip = (v4*)out_ti + tok * 2;
    v4 w0 = { ew[0] * tinv, ew[1] * tinv, ew[2] * tinv, ew[3] * tinv };
    v4 w1 = { ew[4] * tinv, ew[5] * tinv, ew[6] * tinv, ew[7] * tinv };
    v4 i0 = { ids[0], ids[1], ids[2], ids[3] };
    v4 i1 = { ids[4], ids[5], ids[6], ids[7] };
    twp[0] = w0; twp[1] = w1;
    tip[0] = i0; tip[1] = i1;

    #pragma unroll
    for (int j = 0; j < TOPK; ++j)
        atomicAdd(&shist[(int)ids[j]], 1.0f);
    __syncthreads();
    if (tid < NEXP) atomicAdd(&out_hist[tid], shist[tid]);
}

// ---------------- K2: pure streaming passthrough + routing weights ----------------
// Copy-shaped: coalesced v4 read (L3-hot from K1), two coalesced v4 writes.
// No LDS, no sync, tiny VGPR -> copy-level TLP.
__global__ __launch_bounds__(256) void stream_kernel(
    const float* __restrict__ logits,
    const float* __restrict__ sinv_ws,
    float* __restrict__ out_logits,
    float* __restrict__ out_rw,
    long n4)
{
    const long stride = (long)gridDim.x * 256;
    for (long i = (long)blockIdx.x * 256 + threadIdx.x; i < n4; i += stride) {
        v4 x = ((const v4*)logits)[i];
        float si = sinv_ws[i >> 4];           // 16 consecutive threads share -> L1 hit
        ((v4*)out_logits)[i] = x;
        v4 o = { __expf(x.x) * si, __expf(x.y) * si,
                 __expf(x.z) * si, __expf(x.w) * si };
        ((v4*)out_rw)[i] = o;
    }
}

// ---------------- Fallback monolith (R9, proven 104.6us) for tiny ws ----------------
#define TILE 128
#define HPITCH 33
__global__ __launch_bounds__(TILE, 4) void router_mono(
    const float* __restrict__ logits,
    float* __restrict__ out_logits,
    float* __restrict__ out_rw,
    float* __restrict__ out_tw,
    float* __restrict__ out_ti,
    float* __restrict__ out_hist,
    int nTiles)
{
    __shared__ float halfbuf[2][64 * HPITCH];
    __shared__ float shist[NEXP];
    const int tid = threadIdx.x;
    const int w = tid >> 6, l = tid & 63, q = l & 15;
    if (tid < NEXP) shist[tid] = 0.0f;
    __syncthreads();
    float* __restrict__ hb = &halfbuf[w][0];

    #pragma unroll
    for (int t = 0; t < 2; ++t) {
        const int tb = blockIdx.x + t * gridDim.x;
        if (tb >= nTiles) break;
        const long waveBase = (long)tb * TILE + (w << 6);
        const v4* g = (const v4*)logits + waveBase * (NEXP / 4);
        v4 row[16];
        #pragma unroll
        for (int k = 0; k < 16; ++k)
            row[k] = __builtin_nontemporal_load(&g[l + (k << 6)]);
        v4* gp = (v4*)out_logits + waveBase * (NEXP / 4);
        #pragma unroll
        for (int k = 0; k < 16; ++k) gp[l + (k << 6)] = row[k];
        if (q < 8) {
            #pragma unroll
            for (int k = 0; k < 16; ++k) {
                int r = (l >> 4) + (k << 2);
                float* b = &hb[r * HPITCH + (q << 2)];
                v4 v = row[k];
                b[0] = v.x; b[1] = v.y; b[2] = v.z; b[3] = v.w;
            }
        }
        const float* __restrict__ myrow = &hb[l * HPITCH];
        float vals[TOPK], ids[TOPK];
        #pragma unroll
        for (int j = 0; j < TOPK; ++j) { vals[j] = -INFINITY; ids[j] = 0.0f; }
        float ssum = 0.0f;
        #pragma unroll 8
        for (int e = 0; e < 32; ++e) {
            float x = myrow[e];
            ssum += __expf(x);
            float fe = (float)e;
            bool c[TOPK];
            #pragma unroll
            for (int j = 0; j < TOPK; ++j) c[j] = x > vals[j];
            #pragma unroll
            for (int j = TOPK - 1; j >= 1; --j) {
                ids[j]  = c[j] ? (c[j - 1] ? ids[j - 1] : fe) : ids[j];
                vals[j] = __builtin_amdgcn_fmed3f(x, vals[j - 1], vals[j]);
            }
            ids[0]  = c[0] ? fe : ids[0];
            vals[0] = fmaxf(vals[0], x);
        }
        if (q >= 8) {
            #pragma unroll
            for (int k = 0; k < 16; ++k) {
                int r = (l >> 4) + (k << 2);
                float* b = &hb[r * HPITCH + ((q - 8) << 2)];
                v4 v = row[k];
                b[0] = v.x; b[1] = v.y; b[2] = v.z; b[3] = v.w;
            }
        }
        #pragma unroll 8
        for (int e = 32; e < NEXP; ++e) {
            float x = myrow[e - 32];
            ssum += __expf(x);
            float fe = (float)e;
            bool c[TOPK];
            #pragma unroll
            for (int j = 0; j < TOPK; ++j) c[j] = x > vals[j];
            #pragma unroll
            for (int j = TOPK - 1; j >= 1; --j) {
                ids[j]  = c[j] ? (c[j - 1] ? ids[j - 1] : fe) : ids[j];
                vals[j] = __builtin_amdgcn_fmed3f(x, vals[j - 1], vals[j]);
            }
            ids[0]  = c[0] ? fe : ids[0];
            vals[0] = fmaxf(vals[0], x);
        }
        const float sinv = 1.0f / ssum;
        float ew[TOPK];
        float tsum = 0.0f;
        #pragma unroll
        for (int j = 0; j < TOPK; ++j) { ew[j] = __expf(vals[j]); tsum += ew[j]; }
        const float tinv = 1.0f / tsum;
        const long tok = waveBase + l;
        v4* twp = (v4*)out_tw + tok * 2;
        v4* tip = (v4*)out_ti + tok * 2;
        v4 w0 = { ew[0] * tinv, ew[1] * tinv, ew[2] * tinv, ew[3] * tinv };
        v4 w1 = { ew[4] * tinv, ew[5] * tinv, ew[6] * tinv, ew[7] * tinv };
        v4 i0 = { ids[0], ids[1], ids[2], ids[3] };
        v4 i1 = { ids[4], ids[5], ids[6], ids[7] };
        twp[0] = w0; twp[1] = w1; tip[0] = i0; tip[1] = i1;
        #pragma unroll
        for (int j = 0; j < TOPK; ++j)
            atomicAdd(&shist[(int)ids[j]], 1.0f);
        v4* grw = (v4*)out_rw + waveBase * (NEXP / 4);
        #pragma unroll
        for (int k = 0; k < 16; ++k) {
            float si = __shfl(sinv, (l >> 4) + (k << 2));
            v4 x = row[k];
            v4 o = { __expf(x.x) * si, __expf(x.y) * si,
                     __expf(x.z) * si, __expf(x.w) * si };
            grw[l + (k << 6)] = o;
        }
    }
    __syncthreads();
    if (tid < NEXP) atomicAdd(&out_hist[tid], shist[tid]);
}

extern "C" void kernel_launch(void* const* d_in, const int* in_sizes, int n_in,
                              void* d_out, int out_size, void* d_ws, size_t ws_size,
                              hipStream_t stream) {
    const float* logits = (const float*)d_in[0];
    const long T = (long)in_sizes[0] / NEXP;

    float* out      = (float*)d_out;
    float* o_logits = out;
    float* o_rw     = out + T * NEXP;
    float* o_tw     = out + 2 * T * NEXP;
    float* o_ti     = o_tw + T * TOPK;
    float* o_hist   = o_ti + T * TOPK;

    (void)hipMemsetAsync(o_hist, 0, NEXP * sizeof(float), stream);

    if (ws_size >= (size_t)T * sizeof(float)) {
        float* sinv_ws = (float*)d_ws;
        const int grid1 = (int)(T / 256);              // 2048: thread-per-token
        topk_kernel<<<grid1, 256, 0, stream>>>(logits, o_tw, o_ti, o_hist, sinv_ws);
        const long n4 = T * (NEXP / 4);                // 8.4M v4
        stream_kernel<<<2048, 256, 0, stream>>>(logits, sinv_ws, o_logits, o_rw, n4);
    } else {
        const int nTiles = (int)(T / TILE);            // 4096
        const int grid   = (nTiles + 1) / 2;           // 2048
        router_mono<<<grid, TILE, 0, stream>>>(logits, o_logits, o_rw, o_tw, o_ti,
                                               o_hist, nTiles);
    }
}

// Round 11
// 102.895 us; speedup vs baseline: 1.8322x; 1.8322x over previous
//
#include <hip/hip_runtime.h>
#include <math.h>

#define NEXP 64
#define TOPK 8
#define SB 512            // tokens per superblock == block threads
#define PITCH 65          // float pitch: scalar LDS ops -> 2-way banks (free)
#define GRID 256          // 1 block/CU: maximal contiguous stream bursts

typedef float v4 __attribute__((ext_vector_type(4)));

__global__ __launch_bounds__(SB, 2) void router_kernel(
    const float* __restrict__ logits,
    float* __restrict__ out_logits,
    float* __restrict__ out_rw,
    float* __restrict__ out_tw,
    float* __restrict__ out_ti,
    float* __restrict__ out_hist,
    int nSB)
{
    __shared__ float tile[SB * PITCH];    // 133.1 KB: 512 tokens x 64 experts
    __shared__ float srow[SB];            // 1/ssum per token
    __shared__ float shist[NEXP];

    const int tid = threadIdx.x;
    if (tid < NEXP) shist[tid] = 0.0f;    // visible after first in-loop barrier

    const int stride = gridDim.x;
    int s = blockIdx.x;

    // ---- prologue: prefetch superblock s (16 v4/thread, coalesced 8KB/inst) ----
    v4 pre[16];
    {
        const v4* g = (const v4*)logits + (long)s * SB * (NEXP / 4);
        #pragma unroll
        for (int k = 0; k < 16; ++k)
            pre[k] = __builtin_nontemporal_load(&g[tid + (k << 9)]);
    }

    for (; s < nSB; s += stride) {
        const long tokBase = (long)s * SB;
        const long vbase   = tokBase * (NEXP / 4);

        // ---- stage: 256KB contiguous passthrough burst + LDS scatter ----
        v4* gpass = (v4*)out_logits + vbase;
        #pragma unroll
        for (int k = 0; k < 16; ++k) {
            int i = tid + (k << 9);
            v4 v = pre[k];
            gpass[i] = v;
            int r  = i >> 4;
            int c4 = (i & 15) << 2;
            float* b = &tile[r * PITCH + c4];
            b[0] = v.x; b[1] = v.y; b[2] = v.z; b[3] = v.w;
        }
        __syncthreads();

        // ---- issue next superblock's 256KB read burst; flies under the sweep ----
        const int ns = s + stride;
        if (ns < nSB) {
            const v4* g = (const v4*)logits + (long)ns * SB * (NEXP / 4);
            #pragma unroll
            for (int k = 0; k < 16; ++k)
                pre[k] = __builtin_nontemporal_load(&g[tid + (k << 9)]);
        }

        // ---- sweep own token: top-8 insert (strict >, low-index ties) + exp in place ----
        float* __restrict__ row = &tile[tid * PITCH];
        float vals[TOPK], ids[TOPK];
        #pragma unroll
        for (int j = 0; j < TOPK; ++j) { vals[j] = -INFINITY; ids[j] = 0.0f; }
        float ssum = 0.0f;

        #pragma unroll 8
        for (int e = 0; e < NEXP; ++e) {
            float x  = row[e];
            float ev = __expf(x);
            ssum += ev;
            row[e] = ev;                   // overwrite raw with exp(x)
            float fe = (float)e;
            bool c[TOPK];
            #pragma unroll
            for (int j = 0; j < TOPK; ++j) c[j] = x > vals[j];
            #pragma unroll
            for (int j = TOPK - 1; j >= 1; --j) {
                ids[j]  = c[j] ? (c[j - 1] ? ids[j - 1] : fe) : ids[j];
                vals[j] = __builtin_amdgcn_fmed3f(x, vals[j - 1], vals[j]);
            }
            ids[0]  = c[0] ? fe : ids[0];
            vals[0] = fmaxf(vals[0], x);
        }
        const float sinv = 1.0f / ssum;
        srow[tid] = sinv;

        // ---- top-k weights from registers (softmax denominator cancels) ----
        float ew[TOPK];
        float tsum = 0.0f;
        #pragma unroll
        for (int j = 0; j < TOPK; ++j) { ew[j] = __expf(vals[j]); tsum += ew[j]; }
        const float tinv = 1.0f / tsum;

        const long tok = tokBase + tid;
        v4* twp = (v4*)out_tw + tok * 2;
        v4* tip = (v4*)out_ti + tok * 2;
        v4 w0 = { ew[0] * tinv, ew[1] * tinv, ew[2] * tinv, ew[3] * tinv };
        v4 w1 = { ew[4] * tinv, ew[5] * tinv, ew[6] * tinv, ew[7] * tinv };
        v4 i0 = { ids[0], ids[1], ids[2], ids[3] };
        v4 i1 = { ids[4], ids[5], ids[6], ids[7] };
        twp[0] = w0; twp[1] = w1;
        tip[0] = i0; tip[1] = i1;

        // ---- histogram into block-local LDS ----
        #pragma unroll
        for (int j = 0; j < TOPK; ++j)
            atomicAdd(&shist[(int)ids[j]], 1.0f);

        __syncthreads();                   // exp values + srow ready

        // ---- rw: 256KB contiguous write burst from LDS ----
        v4* grw = (v4*)out_rw + vbase;
        #pragma unroll
        for (int k = 0; k < 16; ++k) {
            int i  = tid + (k << 9);
            int r  = i >> 4;
            int c4 = (i & 15) << 2;
            float si = srow[r];
            const float* b = &tile[r * PITCH + c4];
            v4 o = { b[0] * si, b[1] * si, b[2] * si, b[3] * si };
            grw[i] = o;
        }
        __syncthreads();                   // protect tile/srow before next stage
    }

    // ---- flush histogram: one 64-lane global atomic per block (256 blocks) ----
    if (tid < NEXP) atomicAdd(&out_hist[tid], shist[tid]);
}

extern "C" void kernel_launch(void* const* d_in, const int* in_sizes, int n_in,
                              void* d_out, int out_size, void* d_ws, size_t ws_size,
                              hipStream_t stream) {
    const float* logits = (const float*)d_in[0];
    const long T = (long)in_sizes[0] / NEXP;

    float* out      = (float*)d_out;
    float* o_logits = out;
    float* o_rw     = out + T * NEXP;
    float* o_tw     = out + 2 * T * NEXP;
    float* o_ti     = o_tw + T * TOPK;
    float* o_hist   = o_ti + T * TOPK;

    (void)hipMemsetAsync(o_hist, 0, NEXP * sizeof(float), stream);

    const int nSB  = (int)(T / SB);        // 1024
    const int grid = nSB < GRID ? nSB : GRID;
    router_kernel<<<grid, SB, 0, stream>>>(logits, o_logits, o_rw, o_tw, o_ti,
                                           o_hist, nSB);
}

// Round 12
// 88.419 us; speedup vs baseline: 2.1321x; 1.1637x over previous
//
#include <hip/hip_runtime.h>
#include <math.h>

#define NEXP 64
#define TOPK 8
#define TTILE 256          // tokens per tile
#define PITCH 65           // scalar LDS pitch: 2-way banks everywhere (free)
#define NPROD 4            // producer waves; waves 4-7 consume
#define BLKT 512
#define GRID 256           // 1 block/CU; 2048 tiles -> 8 per block exactly

typedef float v4 __attribute__((ext_vector_type(4)));

__global__ __launch_bounds__(BLKT) void router_kernel(
    const float* __restrict__ logits,
    float* __restrict__ out_logits,
    float* __restrict__ out_rw,
    float* __restrict__ out_tw,
    float* __restrict__ out_ti,
    float* __restrict__ out_hist,
    int nT)
{
    __shared__ float lds[2][TTILE * PITCH];   // 133.1 KB double-buffered tiles
    __shared__ float srow[2][TTILE];          // 1/ssum per token
    __shared__ float shist[NEXP];

    const int tid  = threadIdx.x;
    const int wid  = tid >> 6;
    const int l    = tid & 63;
    const bool prod = wid < NPROD;
    if (tid < NEXP) shist[tid] = 0.0f;

    const int G = gridDim.x;
    int tb = blockIdx.x;
    v4 regs[16];

    // ---- prologue: producers load tile tb, pass-store, scatter -> LDS[0] ----
    if (prod && tb < nT) {
        const long base = (long)tb * (TTILE * NEXP / 4);
        const v4* g = (const v4*)logits + base;
        #pragma unroll
        for (int k = 0; k < 16; ++k)
            regs[k] = __builtin_nontemporal_load(&g[(wid << 6) + l + (k << 8)]);
        v4* gp = (v4*)out_logits + base;
        #pragma unroll
        for (int k = 0; k < 16; ++k) {
            int i = (wid << 6) + l + (k << 8);
            v4 v = regs[k];
            gp[i] = v;
            int r = i >> 4, c4 = (i & 15) << 2;
            float* b = &lds[0][r * PITCH + c4];
            b[0] = v.x; b[1] = v.y; b[2] = v.z; b[3] = v.w;
        }
    }
    __syncthreads();

    int it = 0;
    for (; tb < nT; ++it, tb += G) {
        const int cur = it & 1;
        const int nxt = cur ^ 1;
        const int tb_next = tb + G;

        if (prod) {
            // (1) issue next tile's loads first: in flight under everything below
            if (tb_next < nT) {
                const v4* g = (const v4*)logits + (long)tb_next * (TTILE * NEXP / 4);
                #pragma unroll
                for (int k = 0; k < 16; ++k)
                    regs[k] = __builtin_nontemporal_load(&g[(wid << 6) + l + (k << 8)]);
            }
            // (2) rw-write of PREVIOUS tile (exp in LDS[nxt], sinv in srow[nxt])
            if (it > 0) {
                v4* grw = (v4*)out_rw + (long)(tb - G) * (TTILE * NEXP / 4);
                #pragma unroll
                for (int k = 0; k < 16; ++k) {
                    int i = (wid << 6) + l + (k << 8);
                    int r = i >> 4, c4 = (i & 15) << 2;
                    float si = srow[nxt][r];
                    const float* b = &lds[nxt][r * PITCH + c4];
                    v4 o = { b[0] * si, b[1] * si, b[2] * si, b[3] * si };
                    grw[i] = o;
                }
            }
            // (3) pass-store + scatter next tile into LDS[nxt] (after rw reads it)
            if (tb_next < nT) {
                v4* gp = (v4*)out_logits + (long)tb_next * (TTILE * NEXP / 4);
                #pragma unroll
                for (int k = 0; k < 16; ++k) {
                    int i = (wid << 6) + l + (k << 8);
                    v4 v = regs[k];
                    gp[i] = v;
                    int r = i >> 4, c4 = (i & 15) << 2;
                    float* b = &lds[nxt][r * PITCH + c4];
                    b[0] = v.x; b[1] = v.y; b[2] = v.z; b[3] = v.w;
                }
            }
        } else {
            // ---- consumer: sweep own token in LDS[cur] ----
            const int t = ((wid - NPROD) << 6) + l;
            float* __restrict__ row = &lds[cur][t * PITCH];
            float vals[TOPK], ids[TOPK];
            #pragma unroll
            for (int j = 0; j < TOPK; ++j) { vals[j] = -INFINITY; ids[j] = 0.0f; }
            float ssum = 0.0f;

            #pragma unroll 8
            for (int e = 0; e < NEXP; ++e) {
                float x  = row[e];
                float ev = __expf(x);
                ssum += ev;
                row[e] = ev;               // overwrite raw logits with exp(x)
                float fe = (float)e;
                bool c[TOPK];
                #pragma unroll
                for (int j = 0; j < TOPK; ++j) c[j] = x > vals[j];
                #pragma unroll
                for (int j = TOPK - 1; j >= 1; --j) {
                    ids[j]  = c[j] ? (c[j - 1] ? ids[j - 1] : fe) : ids[j];
                    vals[j] = __builtin_amdgcn_fmed3f(x, vals[j - 1], vals[j]);
                }
                ids[0]  = c[0] ? fe : ids[0];
                vals[0] = fmaxf(vals[0], x);
            }
            const float sinv = 1.0f / ssum;
            srow[cur][t] = sinv;

            float ew[TOPK];
            float tsum = 0.0f;
            #pragma unroll
            for (int j = 0; j < TOPK; ++j) { ew[j] = __expf(vals[j]); tsum += ew[j]; }
            const float tinv = 1.0f / tsum;

            const long tok = (long)tb * TTILE + t;
            v4* twp = (v4*)out_tw + tok * 2;
            v4* tip = (v4*)out_ti + tok * 2;
            v4 w0 = { ew[0] * tinv, ew[1] * tinv, ew[2] * tinv, ew[3] * tinv };
            v4 w1 = { ew[4] * tinv, ew[5] * tinv, ew[6] * tinv, ew[7] * tinv };
            v4 i0 = { ids[0], ids[1], ids[2], ids[3] };
            v4 i1 = { ids[4], ids[5], ids[6], ids[7] };
            twp[0] = w0; twp[1] = w1;
            tip[0] = i0; tip[1] = i1;

            #pragma unroll
            for (int j = 0; j < TOPK; ++j)
                atomicAdd(&shist[(int)ids[j]], 1.0f);
        }
        __syncthreads();   // tile swept; next tile staged; srow[cur] published
    }

    // ---- epilogue: rw-write of the final swept tile ----
    if (prod && it > 0) {
        const int lastpar = (it - 1) & 1;
        v4* grw = (v4*)out_rw + (long)(tb - G) * (TTILE * NEXP / 4);
        #pragma unroll
        for (int k = 0; k < 16; ++k) {
            int i = (wid << 6) + l + (k << 8);
            int r = i >> 4, c4 = (i & 15) << 2;
            float si = srow[lastpar][r];
            const float* b = &lds[lastpar][r * PITCH + c4];
            v4 o = { b[0] * si, b[1] * si, b[2] * si, b[3] * si };
            grw[i] = o;
        }
    }
    __syncthreads();
    if (tid < NEXP) atomicAdd(&out_hist[tid], shist[tid]);
}

extern "C" void kernel_launch(void* const* d_in, const int* in_sizes, int n_in,
                              void* d_out, int out_size, void* d_ws, size_t ws_size,
                              hipStream_t stream) {
    const float* logits = (const float*)d_in[0];
    const long T = (long)in_sizes[0] / NEXP;

    float* out      = (float*)d_out;
    float* o_logits = out;
    float* o_rw     = out + T * NEXP;
    float* o_tw     = out + 2 * T * NEXP;
    float* o_ti     = o_tw + T * TOPK;
    float* o_hist   = o_ti + T * TOPK;

    (void)hipMemsetAsync(o_hist, 0, NEXP * sizeof(float), stream);

    const int nT   = (int)(T / TTILE);     // 2048 tiles
    const int grid = nT < GRID ? nT : GRID;
    router_kernel<<<grid, BLKT, 0, stream>>>(logits, o_logits, o_rw, o_tw, o_ti,
                                             o_hist, nT);
}